// Round 1
// baseline (184.883 us; speedup 1.0000x reference)
//
#include <hip/hip_runtime.h>
#include <cstddef>

// Depthwise 7x7 conv, stride 1, pad 3, 4-fold rotational kernel symmetrization.
// x: [16,384,64,64] fp32, w: [384,1,7,7] fp32, out: [16,384,64,64] fp32.
//
// Block = 256 threads, one (n,c) plane per block.
// R2 changes vs R1 (182.7us, 31% occupancy, 7.7M LDS bank conflicts):
//  - 256 threads/block (4 waves share one ~19KB tile): LDS-limited residency
//    8 blocks/CU now = 32 waves = 100% occupancy ceiling (was 16 waves/50%).
//  - Tile row stride padded 64 -> 68 floats: rows 4 apart differ by 16 banks,
//    so per-wave ds_read_b128 aliasing drops 4-way -> 2-way (free, m136).
//  - Output LDS transpose removed (saves 2 barriers + 16 LDS ops/thread);
//    direct stores are 4x 256B contiguous segments per wave instr (dense).
// Thread = 4 cols x 4 consecutive rows: 30 ds_read_b128, 784 FMA.

#define BLOCK 256
#define TS 68                         // padded row stride in floats (16B-aligned)
#define TROWS 70                      // 64 + 2*3 halo rows
#define TILE_F (4 + TROWS * TS)       // 4 guard floats + 70 rows = 4764 floats
// f4 geometry: guard = tile4[0]; row r starts at f4 1 + 17*r.
// front zero: guard + rows 0..2  = f4 [0, 52)
// back  zero: rows 67..69        = f4 [1140, 1191)

// --- compile-time C4 orbit table for the symmetrized 7x7 kernel (13 orbits) ---
constexpr int canon_of(int k) {
    const int i = k / 7, j = k % 7;
    const int a = i * 7 + j;
    const int b = j * 7 + (6 - i);
    const int c = (6 - i) * 7 + (6 - j);
    const int d = (6 - j) * 7 + i;
    int m = a;
    if (b < m) m = b;
    if (c < m) m = c;
    if (d < m) m = d;
    return m;
}
struct Tab { int cidx[49]; };
constexpr Tab build_tab() {
    Tab t{};
    int u = 0;
    for (int k = 0; k < 49; ++k)
        if (canon_of(k) == k) { t.cidx[k] = u; ++u; }
    for (int k = 0; k < 49; ++k) t.cidx[k] = t.cidx[canon_of(k)];
    return t;
}
constexpr Tab TAB = build_tab();

__global__ __launch_bounds__(BLOCK, 8) void dwconv7_sym_kernel(
    const float* __restrict__ x, const float* __restrict__ w,
    float* __restrict__ out, int C)
{
    __shared__ __align__(16) float tile[TILE_F];
    __shared__ float wsym[49];
    float4* const tile4 = (float4*)tile;     // 1191 float4 slots

    const int plane = blockIdx.x;            // n*C + c
    const int c = plane % C;
    const int tid = threadIdx.x;

    // --- issue global loads early: 4 float4 per thread, contiguous wave runs ---
    const float4* __restrict__ xp4 = (const float4*)(x + (size_t)plane * 4096);
    float4 gv[4];
    #pragma unroll
    for (int k = 0; k < 4; ++k)
        gv[k] = xp4[k * BLOCK + tid];        // 1024 float4 = whole plane

    // --- zero halo rows (row pads are never consumed: edge masks cover them) ---
    if (tid < 52) tile4[tid] = make_float4(0.f, 0.f, 0.f, 0.f);
    if (tid >= 64 && tid < 115) tile4[1140 + (tid - 64)] = make_float4(0.f, 0.f, 0.f, 0.f);

    // --- symmetrize weights ---
    if (tid < 49) {
        const int i = tid / 7;
        const int j = tid - i * 7;
        const float* wc = w + c * 49;
        wsym[tid] = 0.25f * (wc[i * 7 + j]
                           + wc[j * 7 + (6 - i)]
                           + wc[(6 - i) * 7 + (6 - j)]
                           + wc[(6 - j) * 7 + i]);
    }

    // --- interior: plane f4 g = (grow,gcol) lands at tile4[1 + (grow+3)*17 + gcol] ---
    #pragma unroll
    for (int k = 0; k < 4; ++k) {
        const int g = k * BLOCK + tid;
        const int grow = g >> 4;
        const int gcol = g & 15;
        tile4[1 + (grow + 3) * 17 + gcol] = gv[k];
    }
    __syncthreads();

    // --- 13 unique weights -> registers (broadcast reads) ---
    float wu[13];
    #pragma unroll
    for (int k = 0; k < 49; ++k)
        if (canon_of(k) == k) wu[TAB.cidx[k]] = wsym[k];

    // --- compute: thread = cols 4cg..4cg+3, out rows 4S..4S+3 ---
    const int cg = tid & 15;
    const int S  = tid >> 4;                 // 0..15
    const int x0 = 4 * cg;
    // out[y][x0+d] = sum_{i,j} tile_row(y+i) col(x0+d+j-3) * w[i][j]
    // float addr (incl guard) = (y+i)*TS + x0 + (d+j+1) - 4 + 4

    float acc[4][4];
    #pragma unroll
    for (int t = 0; t < 4; ++t)
        #pragma unroll
        for (int d = 0; d < 4; ++d) acc[t][d] = 0.f;

    #pragma unroll
    for (int ro = 0; ro < 10; ++ro) {
        const int row = 4 * S + ro;
        const float4* p4 = (const float4*)(tile + row * TS + x0);  // cols x0-4..x0+11
        float4 a = p4[0], b = p4[1], cc = p4[2];
        if (cg == 0)  { a.x = 0.f; a.y = 0.f; a.z = 0.f; a.w = 0.f; }  // cols <0
        if (cg == 15) { cc.x = 0.f; cc.y = 0.f; cc.z = 0.f; }          // cols >=64
        const float r[12] = {a.x, a.y, a.z, a.w, b.x, b.y, b.z, b.w,
                             cc.x, cc.y, cc.z, cc.w};
        #pragma unroll
        for (int t = 0; t < 4; ++t) {
            if (t <= ro && ro <= t + 6) {          // constant after unroll
                const int i = ro - t;              // kernel row
                #pragma unroll
                for (int d = 0; d < 4; ++d)
                    #pragma unroll
                    for (int j = 0; j < 7; ++j)
                        acc[t][d] += r[d + j + 1] * wu[TAB.cidx[i * 7 + j]];
            }
        }
    }

    // --- direct stores: per wave instr = 4x 256B contiguous segments (dense) ---
    float4* __restrict__ op4 = (float4*)(out + (size_t)plane * 4096);
    #pragma unroll
    for (int t = 0; t < 4; ++t) {
        float4 v;
        v.x = acc[t][0]; v.y = acc[t][1]; v.z = acc[t][2]; v.w = acc[t][3];
        op4[(4 * S + t) * 16 + cg] = v;
    }
}

extern "C" void kernel_launch(void* const* d_in, const int* in_sizes, int n_in,
                              void* d_out, int out_size, void* d_ws, size_t ws_size,
                              hipStream_t stream) {
    const float* x = (const float*)d_in[0];
    const float* w = (const float*)d_in[1];
    float* out = (float*)d_out;

    const int planes = in_sizes[0] / 4096;   // N*C = 6144
    const int C = in_sizes[1] / 49;          // 384

    dwconv7_sym_kernel<<<dim3(planes), dim3(BLOCK), 0, stream>>>(x, w, out, C);
}